// Round 7
// baseline (261.638 us; speedup 1.0000x reference)
//
#include <hip/hip_runtime.h>
#include <hip/hip_bf16.h>

// Max-margin (hinge) criterion — wave-per-row, barrier-free, nontemporal.
//
// Model so far: reads are capped by per-CU outstanding-line tracking x
// effective latency (~2.3 TB/s plain, ~3.7 TB/s with nt loads). Wave-level
// MLP is over-provisioned. The last structural coupling is the block-wide
// __syncthreads: all 4 waves stall on the slowest wave's vmcnt(0). Here one
// 64-lane wave owns exactly one row (64 lanes x 8 float4 = 2048 cols):
//   - 8 int4 (target) + 8 float4 (cossim) nt loads issued up front;
//   - the one-hot hit lane already holds the correct similarity in regs;
//   - 6-step shuffle max-broadcast (no LDS, no barrier);
//   - hinge from registers, wave-shuffle sum, plain store per wave;
//   - tiny final kernel reduces 16384 partials.

constexpr int   kC      = 2048;
constexpr float kMargin = 0.1f;
constexpr int   kBatch  = 8;     // 16B chunks per lane: 64*8*4 = 2048 = one row

typedef float f32x4 __attribute__((ext_vector_type(4)));
typedef int   i32x4 __attribute__((ext_vector_type(4)));

__global__ __launch_bounds__(256) void max_margin_main(
    const f32x4* __restrict__ cossim4,
    const i32x4* __restrict__ target4,
    float*       __restrict__ partials)
{
    const int lane = threadIdx.x & 63;
    const int wib  = threadIdx.x >> 6;
    const int row  = blockIdx.x * 4 + wib;          // wave id == row
    const size_t base = (size_t)row * (kC / 4);     // 16B-chunk units

    // Issue all 16 independent nontemporal 16B loads back-to-back.
    i32x4 t[kBatch];
    f32x4 c[kBatch];
    #pragma unroll
    for (int k = 0; k < kBatch; ++k) {
        size_t g = base + k * 64 + lane;
        t[k] = __builtin_nontemporal_load(&target4[g]);
        c[k] = __builtin_nontemporal_load(&cossim4[g]);
    }

    // Hit lane extracts the correct similarity from its own registers.
    float sim = -3.0e38f;
    #pragma unroll
    for (int k = 0; k < kBatch; ++k) {
        if ((t[k].x | t[k].y | t[k].z | t[k].w) != 0) {
            sim = t[k].x ? c[k].x : (t[k].y ? c[k].y
                : (t[k].z ? c[k].z : c[k].w));
        }
    }
    // Broadcast across the wave (exactly one lane found it) — no barrier.
    #pragma unroll
    for (int o = 32; o > 0; o >>= 1)
        sim = fmaxf(sim, __shfl_xor(sim, o));

    // Hinge accumulate from registers.
    float s = 0.0f;
    #pragma unroll
    for (int k = 0; k < kBatch; ++k) {
        float m = kMargin - sim;
        s += fmaxf(m + c[k].x, 0.0f);
        s += fmaxf(m + c[k].y, 0.0f);
        s += fmaxf(m + c[k].z, 0.0f);
        s += fmaxf(m + c[k].w, 0.0f);
    }

    // Wave reduce; one plain store per wave (no atomics, no LDS).
    #pragma unroll
    for (int o = 32; o > 0; o >>= 1)
        s += __shfl_xor(s, o);
    if (lane == 0)
        partials[row] = s;
}

// Final reduce: 16384 partials -> scalar mean, subtracting the
// correct-choice term (exactly kMargin per row).
__global__ __launch_bounds__(256) void final_reduce(
    const float* __restrict__ partials,
    float*       __restrict__ out,
    int nparts, float inv_n)
{
    const int tid = threadIdx.x;
    float s = 0.0f;
    for (int i = tid; i < nparts; i += 256)
        s += partials[i];

    #pragma unroll
    for (int o = 32; o > 0; o >>= 1)
        s += __shfl_xor(s, o);

    __shared__ float ws[4];
    const int lane = tid & 63;
    const int wib  = tid >> 6;
    if (lane == 0) ws[wib] = s;
    __syncthreads();
    if (tid == 0)
        out[0] = (ws[0] + ws[1] + ws[2] + ws[3]) * inv_n - kMargin;
}

extern "C" void kernel_launch(void* const* d_in, const int* in_sizes, int n_in,
                              void* d_out, int out_size, void* d_ws, size_t ws_size,
                              hipStream_t stream)
{
    const float* cossim = (const float*)d_in[0];
    const int*   target = (const int*)d_in[1];
    float*       out    = (float*)d_out;
    float*       parts  = (float*)d_ws;          // nrows floats of scratch

    const int nrows = in_sizes[0] / kC;          // 16384

    max_margin_main<<<nrows / 4, 256, 0, stream>>>(
        (const f32x4*)cossim, (const i32x4*)target, parts);
    final_reduce<<<1, 256, 0, stream>>>(parts, out, nrows,
                                        1.0f / (float)nrows);
}

// Round 8
// 253.620 us; speedup vs baseline: 1.0316x; 1.0316x over previous
//
#include <hip/hip_runtime.h>
#include <hip/hip_bf16.h>

// Max-margin (hinge) criterion — REVERT to R6 (measured best, 250 us bench).
//
// Final model: mandatory traffic = 256 MiB (cossim fp32 + one-hot target
// int32, each read exactly once). Pure-read throughput on this part plateaus
// at ~2.5 TB/s with plain loads and ~3.7 TB/s with nontemporal loads — a
// read-concurrency/fabric ceiling that batching (R4), atomic elimination
// (R5), and barrier elimination (R7, regressed) all failed to move.
// Structure: block owns 4 rows; 16 upfront nt loads/thread; the one-hot hit
// thread publishes the correct sim via LDS (one barrier, hidden by ~20
// resident waves/CU); hinge from registers; no atomics (plain partial store
// + tiny final reduce).

constexpr int   kC      = 2048;
constexpr float kMargin = 0.1f;
constexpr int   kBatch  = 8;     // 16B chunks per thread => 4 rows per block

typedef float f32x4 __attribute__((ext_vector_type(4)));
typedef int   i32x4 __attribute__((ext_vector_type(4)));

__global__ __launch_bounds__(256) void max_margin_main(
    const f32x4* __restrict__ cossim4,
    const i32x4* __restrict__ target4,
    float*       __restrict__ partials)
{
    const int tid = threadIdx.x;
    const size_t base = (size_t)blockIdx.x * (kBatch * 256);   // 16B-chunk units

    // Issue all 16 independent 16B nontemporal loads back-to-back.
    i32x4 t[kBatch];
    f32x4 c[kBatch];
    #pragma unroll
    for (int k = 0; k < kBatch; ++k) {
        size_t g = base + k * 256 + tid;
        t[k] = __builtin_nontemporal_load(&target4[g]);
        c[k] = __builtin_nontemporal_load(&cossim4[g]);
    }

    // Phase 1: hit thread publishes the correct similarity for its row.
    // Local row for chunk k is the compile-time constant k>>1.
    __shared__ float s_sim[4];
    #pragma unroll
    for (int k = 0; k < kBatch; ++k) {
        if ((t[k].x | t[k].y | t[k].z | t[k].w) != 0) {
            float v = t[k].x ? c[k].x : (t[k].y ? c[k].y
                    : (t[k].z ? c[k].z : c[k].w));
            s_sim[k >> 1] = v;
        }
    }
    __syncthreads();

    // Phase 2: hinge accumulate (cossim already in registers).
    float s = 0.0f;
    #pragma unroll
    for (int k = 0; k < kBatch; ++k) {
        float m = kMargin - s_sim[k >> 1];
        s += fmaxf(m + c[k].x, 0.0f);
        s += fmaxf(m + c[k].y, 0.0f);
        s += fmaxf(m + c[k].z, 0.0f);
        s += fmaxf(m + c[k].w, 0.0f);
    }

    // wave reduce (64 lanes)
    #pragma unroll
    for (int o = 32; o > 0; o >>= 1)
        s += __shfl_xor(s, o);

    // block reduce (4 waves) -> ONE plain store per block, no atomic
    __shared__ float ws[4];
    const int lane = tid & 63;
    const int wib  = tid >> 6;
    if (lane == 0) ws[wib] = s;
    __syncthreads();
    if (tid == 0)
        __builtin_nontemporal_store(ws[0] + ws[1] + ws[2] + ws[3],
                                    &partials[blockIdx.x]);
}

// Final reduce: 4096 partials -> scalar mean (subtracting the correct-choice
// term, which is exactly kMargin per row).
__global__ __launch_bounds__(256) void final_reduce(
    const float* __restrict__ partials,
    float*       __restrict__ out,
    int nparts, float inv_n)
{
    const int tid = threadIdx.x;
    float s = 0.0f;
    for (int i = tid; i < nparts; i += 256)
        s += partials[i];

    #pragma unroll
    for (int o = 32; o > 0; o >>= 1)
        s += __shfl_xor(s, o);

    __shared__ float ws[4];
    const int lane = tid & 63;
    const int wib  = tid >> 6;
    if (lane == 0) ws[wib] = s;
    __syncthreads();
    if (tid == 0)
        out[0] = (ws[0] + ws[1] + ws[2] + ws[3]) * inv_n - kMargin;
}

extern "C" void kernel_launch(void* const* d_in, const int* in_sizes, int n_in,
                              void* d_out, int out_size, void* d_ws, size_t ws_size,
                              hipStream_t stream)
{
    const float* cossim = (const float*)d_in[0];
    const int*   target = (const int*)d_in[1];
    float*       out    = (float*)d_out;
    float*       parts  = (float*)d_ws;

    const int nrows  = in_sizes[0] / kC;                 // 16384
    const int blocks = in_sizes[0] / (kBatch * 256 * 4); // 4096

    max_margin_main<<<blocks, 256, 0, stream>>>(
        (const f32x4*)cossim, (const i32x4*)target, parts);
    final_reduce<<<1, 256, 0, stream>>>(parts, out, blocks,
                                        1.0f / (float)nrows);
}